// Round 13
// baseline (114.530 us; speedup 1.0000x reference)
//
#include <hip/hip_runtime.h>
#include <hip/hip_bf16.h>

// Problem constants (fixed by the reference)
#define NROWS 16384
#define SEQD  512
#define HIDD  1024
#define ENCD  256
#define NEXP  8
#define NBLK  64                  // bucketing blocks (256 rows each)
#define MAXTILES 136              // 16384/128 + 8 (one partial tile per expert)
#define MPAD_MAX (MAXTILES * 128) // 17408

using bf16 = __hip_bfloat16;
typedef __bf16 bf16x8 __attribute__((ext_vector_type(8)));
typedef float  f32x4  __attribute__((ext_vector_type(4)));

// XCD-aware bijective blockIdx.x swizzle (grid.x % 8 == 0 for all our GEMMs)
__device__ __forceinline__ int xcd_swz(int bx, int gx) {
  const int cpx = gx >> 3;
  return (bx & 7) * cpx + (bx >> 3);
}

// ---------------- workspace layout (bytes) ----------------
enum : size_t {
  OFF_XB   = 0,                                  // 16384*512*2
  OFF_W1T  = OFF_XB  + (size_t)NROWS * SEQD * 2,
  OFF_W2T  = OFF_W1T + (size_t)HIDD * SEQD * 2,
  OFF_H    = OFF_W2T + (size_t)ENCD * HIDD * 2,
  OFF_W3T  = OFF_H   + (size_t)NROWS * HIDD * 2,
  OFF_W4T  = OFF_W3T + (size_t)NEXP * HIDD * ENCD * 2,
  OFF_Z    = OFF_W4T + (size_t)NEXP * SEQD * HIDD * 2,
  OFF_PERM = OFF_Z   + (size_t)NROWS * ENCD * 2,
  OFF_META = OFF_PERM + (size_t)MPAD_MAX * 4,
  OFF_U    = 0,
  WS_NEED  = OFF_META + 8192
};
// meta int layout: [0..511]=gh (per-block hist, 64x8), [512..520]=bases[9]

__device__ __forceinline__ void gload_lds16(const void* g, void* l) {
  __builtin_amdgcn_global_load_lds(
      (const __attribute__((address_space(1))) void*)g,
      (__attribute__((address_space(3))) void*)l, 16, 0, 0);
}

// ---------------- fused prep: x->bf16 + 4 weight transposes + ids histogram ----------------
// block ranges: [0,4096) cvtx | weights: +512 W1, +256 W2, +2048 W3, +4096 W4 | +64 hist
__global__ void prep_k(const float* __restrict__ x,
                       const float* __restrict__ W1, const float* __restrict__ W2,
                       const float* __restrict__ W3, const float* __restrict__ W4,
                       const int* __restrict__ ids,
                       bf16* __restrict__ Xb, bf16* __restrict__ W1t,
                       bf16* __restrict__ W2t, bf16* __restrict__ W3t,
                       bf16* __restrict__ W4t, int* __restrict__ gh) {
  __shared__ float t[32][33];
  int b = blockIdx.x;
  const int tid = threadIdx.x;
  if (b < 4096) {  // x -> bf16, 8 f32/thread (streaming, full TLP)
    size_t i = (size_t)b * 256 + tid;
    float4 a = ((const float4*)x)[i * 2];
    float4 c = ((const float4*)x)[i * 2 + 1];
    __align__(16) bf16 v[8] = {
      __float2bfloat16(a.x), __float2bfloat16(a.y), __float2bfloat16(a.z), __float2bfloat16(a.w),
      __float2bfloat16(c.x), __float2bfloat16(c.y), __float2bfloat16(c.z), __float2bfloat16(c.w)};
    *(int4*)(Xb + i * 8) = *(const int4*)v;
    return;
  }
  b -= 4096;
  if (b >= 6912) {  // ids histogram (order-invariant LDS atomics)
    __shared__ int c[NEXP];
    if (tid < NEXP) c[tid] = 0;
    __syncthreads();
    atomicAdd(&c[ids[(b - 6912) * 256 + tid]], 1);
    __syncthreads();
    if (tid < NEXP) gh[(b - 6912) * NEXP + tid] = c[tid];
    return;
  }
  const float* s; bf16* d; int R, C;
  if (b < 512)              { s = W1; d = W1t; R = SEQD; C = HIDD; }
  else if ((b -= 512) < 256){ s = W2; d = W2t; R = HIDD; C = ENCD; }
  else if ((b -= 256) < 2048){
    int z = b >> 8; b &= 255; s = W3 + (size_t)z * ENCD * HIDD; d = W3t + (size_t)z * ENCD * HIDD;
    R = ENCD; C = HIDD;
  } else {
    b -= 2048; int z = b >> 9; b &= 511;
    s = W4 + (size_t)z * HIDD * SEQD; d = W4t + (size_t)z * HIDD * SEQD;
    R = HIDD; C = SEQD;
  }
  const int nbx = C >> 5;
  const int bx = (b % nbx) * 32, by = (b / nbx) * 32;
  const int tx = tid & 31, ty = tid >> 5;
  #pragma unroll
  for (int i = 0; i < 32; i += 8) t[ty + i][tx] = s[(size_t)(by + ty + i) * C + bx + tx];
  __syncthreads();
  #pragma unroll
  for (int i = 0; i < 32; i += 8)
    d[(size_t)(bx + ty + i) * R + by + tx] = __float2bfloat16(t[tx][ty + i]);
}

// ---------------- 128x128 bf16 MFMA GEMM, N-slot counted-vmcnt (round-7/8-proven) ----------------
template <bool GATHER_A, bool EXPERT, bool RELU, bool SCATTER_F32, int NSLOTS>
__global__ __launch_bounds__(256, (NSLOTS == 2 ? 2 : 1)) void gemm128(
    const bf16* __restrict__ A, const bf16* __restrict__ Bt,
    const float* __restrict__ bias, void* __restrict__ Out,
    int Ncols, int K, const int* __restrict__ perm, const int* __restrict__ bases) {
  __shared__ char lds[NSLOTS * 32768];  // slots x (A 16KB | B 16KB); byte^=(row&7)<<4 swizzle

  const int tid  = threadIdx.x;
  const int wid  = tid >> 6;
  const int lane = tid & 63;
  const int lm = lane & 15, l4 = lane >> 4;
  const int wm = wid >> 1, wn = wid & 1;

  const int tileM = xcd_swz(blockIdx.x, gridDim.x), tileN = blockIdx.y;
  int expert = 0;
  if (EXPERT) {
    const int total = bases[8];
    if (tileM * 128 >= total) return;  // uniform early-exit, before any barrier
    const int r0 = tileM * 128;
    #pragma unroll
    for (int e = 1; e < NEXP; ++e) expert += (r0 >= bases[e]) ? 1 : 0;
    Bt   += (size_t)expert * Ncols * K;
    bias += expert * Ncols;
  }
  const int row0 = tileM * 128, col0 = tileN * 128;

  const bf16* gA[4];
  const bf16* gB[4];
  #pragma unroll
  for (int i = 0; i < 4; ++i) {
    int flat = (i * 4 + wid) * 1024 + lane * 16;
    int r    = flat >> 7;
    int cb   = (flat & 127) ^ ((r & 7) << 4);
    int arow;
    if (GATHER_A) {
      int p = perm[row0 + r];
      arow = (p < 0) ? 0 : p;
    } else {
      arow = row0 + r;
    }
    gA[i] = A  + (size_t)arow * K + (cb >> 1);
    gB[i] = Bt + (size_t)(col0 + r) * K + (cb >> 1);
  }

  f32x4 acc[4][4];
  #pragma unroll
  for (int i = 0; i < 4; ++i)
    #pragma unroll
    for (int j = 0; j < 4; ++j) { f32x4 z = {0.f, 0.f, 0.f, 0.f}; acc[i][j] = z; }

  int aoff[4], boff[4];
  const int swz = (lm & 7) << 4;
  #pragma unroll
  for (int i = 0; i < 4; ++i) {
    int ar = wm * 64 + i * 16 + lm;
    aoff[i] = ar * 128 + ((l4 * 16) ^ swz);
    int br = wn * 64 + i * 16 + lm;
    boff[i] = br * 128 + ((l4 * 16) ^ swz);
  }

  const int nk = K >> 6;
  asm volatile("s_waitcnt vmcnt(0)" ::: "memory");
  __builtin_amdgcn_sched_barrier(0);

  #pragma unroll
  for (int s = 0; s < NSLOTS; ++s) {
    if (s < nk) {
      #pragma unroll
      for (int i = 0; i < 4; ++i) {
        gload_lds16(gA[i] + (size_t)s * 64, lds + s * 32768 + (i * 4 + wid) * 1024);
        gload_lds16(gB[i] + (size_t)s * 64, lds + s * 32768 + 16384 + (i * 4 + wid) * 1024);
      }
    }
  }

  int slot = 0;
  for (int kt = 0; kt < nk; ++kt) {
    int inflight = nk - 1 - kt;
    if (inflight > NSLOTS - 1) inflight = NSLOTS - 1;
    if (inflight >= 2)      asm volatile("s_waitcnt vmcnt(16)" ::: "memory");
    else if (inflight == 1) asm volatile("s_waitcnt vmcnt(8)"  ::: "memory");
    else                    asm volatile("s_waitcnt vmcnt(0)"  ::: "memory");
    asm volatile("s_barrier" ::: "memory");
    __builtin_amdgcn_sched_barrier(0);

    const char* Ac = lds + slot * 32768;
    const char* Bc = Ac + 16384;
    #pragma unroll
    for (int kk = 0; kk < 2; ++kk) {
      bf16x8 af[4], bfr[4];
      #pragma unroll
      for (int i = 0; i < 4; ++i) af[i]  = *(const bf16x8*)(Ac + (aoff[i] ^ (kk * 64)));
      #pragma unroll
      for (int i = 0; i < 4; ++i) bfr[i] = *(const bf16x8*)(Bc + (boff[i] ^ (kk * 64)));
      __builtin_amdgcn_s_setprio(1);
      #pragma unroll
      for (int mi = 0; mi < 4; ++mi)
        #pragma unroll
        for (int ni = 0; ni < 4; ++ni)
          acc[mi][ni] = __builtin_amdgcn_mfma_f32_16x16x32_bf16(af[mi], bfr[ni], acc[mi][ni], 0, 0, 0);
      __builtin_amdgcn_s_setprio(0);
    }

    asm volatile("s_barrier" ::: "memory");
    __builtin_amdgcn_sched_barrier(0);
    if (kt + NSLOTS < nk) {
      char* An = lds + slot * 32768;
      #pragma unroll
      for (int i = 0; i < 4; ++i) {
        gload_lds16(gA[i] + (size_t)(kt + NSLOTS) * 64, An + (i * 4 + wid) * 1024);
        gload_lds16(gB[i] + (size_t)(kt + NSLOTS) * 64, An + 16384 + (i * 4 + wid) * 1024);
      }
    }
    slot = (slot + 1 == NSLOTS) ? 0 : slot + 1;
  }

  float bv[4];
  #pragma unroll
  for (int ni = 0; ni < 4; ++ni) bv[ni] = bias[col0 + wn * 64 + ni * 16 + lm];
  #pragma unroll
  for (int mi = 0; mi < 4; ++mi) {
    #pragma unroll
    for (int r = 0; r < 4; ++r) {
      int rowp = row0 + wm * 64 + mi * 16 + l4 * 4 + r;
      int orow = rowp;
      bool valid = true;
      if (SCATTER_F32) {
        int p = perm[rowp];
        valid = (p >= 0);
        orow  = valid ? p : 0;
      }
      #pragma unroll
      for (int ni = 0; ni < 4; ++ni) {
        float v = acc[mi][ni][r] + bv[ni];
        if (RELU) v = v > 0.f ? v : 0.f;
        int n = col0 + wn * 64 + ni * 16 + lm;
        if (SCATTER_F32) {
          if (valid) ((float*)Out)[(size_t)orow * Ncols + n] = v;
        } else {
          ((bf16*)Out)[(size_t)rowp * Ncols + n] = __float2bfloat16(v);
        }
      }
    }
  }
}

// ---------------- 256x256 8-wave phase-locked GEMM (G1) + embedded bucketing stripe ----------------
__global__ __launch_bounds__(512, 2) void gemm256p(
    const bf16* __restrict__ A, const bf16* __restrict__ Bt,
    const float* __restrict__ bias, bf16* __restrict__ Out, int Ncols, int K,
    const int* __restrict__ ids, const int* __restrict__ gh,
    int* __restrict__ perm, int* __restrict__ bases_g) {
  __shared__ char lds[131072];

  const int tid  = threadIdx.x;

  if (blockIdx.y == 4) {  // ---- bucketing stripe (round-11-proven) ----
    __shared__ int counts_s[NEXP];
    __shared__ int base_s[NEXP + 1];
    __shared__ int myb[NEXP];
    __shared__ int wavehist[4][NEXP];
    const int bx = blockIdx.x;  // 0..63
    if (tid < NEXP) {
      int s = 0, run = 0;
      for (int b = 0; b < NBLK; ++b) {
        int g = gh[b * NEXP + tid];
        if (b < bx) run += g;
        s += g;
      }
      counts_s[tid] = s;
      myb[tid] = run;
    }
    __syncthreads();
    if (tid == 0) {
      int t = 0;
      for (int e = 0; e < NEXP; ++e) { base_s[e] = t; t += (counts_s[e] + 127) & ~127; }
      base_s[NEXP] = t;
    }
    __syncthreads();
    if (tid < NEXP) myb[tid] += base_s[tid];
    if (bx == 0) {
      if (tid <= NEXP) bases_g[tid] = base_s[tid];
      #pragma unroll
      for (int e = 0; e < NEXP; ++e) {
        int i = base_s[e] + counts_s[e] + tid;
        if (i < base_s[e + 1]) perm[i] = -1;
      }
    }
    __syncthreads();
    const int w = tid >> 6, lane = tid & 63;
    const unsigned long long lt = (1ull << lane) - 1ull;
    int e = 0, myrank = 0;
    if (w < 4) {
      e = ids[bx * 256 + tid];
      #pragma unroll
      for (int ee = 0; ee < NEXP; ++ee) {
        unsigned long long bb = __ballot(e == ee);
        if (ee == e) myrank = __popcll(bb & lt);
        if (lane == 0) wavehist[w][ee] = __popcll(bb);
      }
    }
    __syncthreads();
    if (w < 4) {
      int pre = 0;
      for (int w2 = 0; w2 < w; ++w2) pre += wavehist[w2][e];
      perm[myb[e] + pre + myrank] = bx * 256 + tid;
    }
    return;
  }

  // ---- GEMM path (round-10-proven) ----
  const int wid  = tid >> 6;
  const int lane = tid & 63;
  const int lm = lane & 15, l4 = lane >> 4;
  const int wm = wid >> 2, wn = wid & 3;
  const int tileM = xcd_swz(blockIdx.x, gridDim.x);
  const int row0 = tileM * 256, col0 = blockIdx.y * 256;

  const bf16* gA[4];
  const bf16* gB[4];
  #pragma unroll
  for (int i = 0; i < 4; ++i) {
    const int flat = i * 8192 + tid * 16;
    const int r    = flat >> 7;
    const int cb   = (flat & 127) ^ ((r & 7) << 4);
    gA[i] = A  + (size_t)(row0 + r) * K + (cb >> 1);
    gB[i] = Bt + (size_t)(col0 + r) * K + (cb >> 1);
  }

  f32x4 acc[8][4];
  #pragma unroll
  for (int i = 0; i < 8; ++i)
    #pragma unroll
    for (int j = 0; j < 4; ++j) { f32x4 z = {0.f, 0.f, 0.f, 0.f}; acc[i][j] = z; }

  int aoff[2][4], boff[2][2];
  #pragma unroll
  for (int h = 0; h < 2; ++h)
    #pragma unroll
    for (int q = 0; q < 4; ++q) {
      int row = wm * 128 + h * 64 + q * 16 + lm;
      aoff[h][q] = row * 128 + ((l4 * 16) ^ ((row & 7) << 4));
    }
  #pragma unroll
  for (int nh = 0; nh < 2; ++nh)
    #pragma unroll
    for (int p = 0; p < 2; ++p) {
      int row = wn * 64 + nh * 32 + p * 16 + lm;
      boff[nh][p] = row * 128 + ((l4 * 16) ^ ((row & 7) << 4));
    }

  const int nk = K >> 6;
  asm volatile("s_waitcnt vmcnt(0)" ::: "memory");
  __builtin_amdgcn_sched_barrier(0);

  #pragma unroll
  for (int i = 0; i < 4; ++i) {
    gload_lds16(gA[i], lds + i * 8192 + tid * 16);
    gload_lds16(gB[i], lds + 32768 + i * 8192 + tid * 16);
  }
  #pragma unroll
  for (int i = 0; i < 4; ++i) {
    gload_lds16(gA[i] + 64, lds + 65536 + i * 8192 + tid * 16);
    gload_lds16(gB[i] + 64, lds + 65536 + 32768 + i * 8192 + tid * 16);
  }
  asm volatile("s_waitcnt vmcnt(8)" ::: "memory");
  asm volatile("s_barrier" ::: "memory");
  __builtin_amdgcn_sched_barrier(0);

  bf16x8 a[4][2], b[2][2];
  #pragma unroll
  for (int q = 0; q < 4; ++q)
    #pragma unroll
    for (int kk = 0; kk < 2; ++kk) a[q][kk] = *(const bf16x8*)(lds + (aoff[0][q] ^ (kk * 64)));
  #pragma unroll
  for (int p = 0; p < 2; ++p)
    #pragma unroll
    for (int kk = 0; kk < 2; ++kk) b[p][kk] = *(const bf16x8*)(lds + 32768 + (boff[0][p] ^ (kk * 64)));

#define MFMA16(MOFF, NOFF)                                                      \
  __builtin_amdgcn_s_setprio(1);                                                \
  _Pragma("unroll")                                                             \
  for (int kk = 0; kk < 2; ++kk)                                                \
    _Pragma("unroll")                                                           \
    for (int mf = 0; mf < 4; ++mf)                                              \
      _Pragma("unroll")                                                         \
      for (int nf = 0; nf < 2; ++nf)                                            \
        acc[MOFF + mf][NOFF + nf] = __builtin_amdgcn_mfma_f32_16x16x32_bf16(    \
            a[mf][kk], b[nf][kk], acc[MOFF + mf][NOFF + nf], 0, 0, 0);          \
  __builtin_amdgcn_s_setprio(0);

#define RD_A(H, BUFA)                                                           \
  _Pragma("unroll")                                                             \
  for (int q = 0; q < 4; ++q)                                                   \
    _Pragma("unroll")                                                           \
    for (int kk = 0; kk < 2; ++kk)                                              \
      a[q][kk] = *(const bf16x8*)((BUFA) + (aoff[H][q] ^ (kk * 64)));
#define RD_B(NH, BUFB)                                                          \
  _Pragma("unroll")                                                             \
  for (int p = 0; p < 2; ++p)                                                   \
    _Pragma("unroll")                                                           \
    for (int kk = 0; kk < 2; ++kk)                                              \
      b[p][kk] = *(const bf16x8*)((BUFB) + (boff[NH][p] ^ (kk * 64)));

  for (int kt = 0; kt < nk; ++kt) {
    const char* bufA = lds + (kt & 1) * 65536;
    const char* bufB = bufA + 32768;
    asm volatile("s_barrier" ::: "memory");
    MFMA16(0, 0)
    RD_B(1, bufB)
    asm volatile("s_barrier" ::: "memory");
    MFMA16(0, 2)
    RD_A(1, bufA)
    asm volatile("s_barrier" ::: "memory");
    MFMA16(4, 2)
    RD_B(0, bufB)
    asm volatile("s_barrier" ::: "memory");
    MFMA16(4, 0)
    if (kt + 1 < nk) {
      asm volatile("s_waitcnt lgkmcnt(0)" ::: "memory");
      asm volatile("s_barrier" ::: "memory");
      __builtin_amdgcn_sched_barrier(0);
      if (kt + 2 < nk) {
        char* sA = lds + (kt & 1) * 65536;
        #pragma unroll
        for (int i = 0; i < 4; ++i) {
          gload_lds16(gA[i] + (size_t)(kt + 2) * 64, sA + i * 8192 + tid * 16);
          gload_lds16(gB[i] + (size_t)(kt + 2) * 64, sA + 32768 + i * 8192 + tid * 16);
        }
        asm volatile("s_waitcnt vmcnt(8)" ::: "memory");
      } else {
        asm volatile("s_waitcnt vmcnt(0)" ::: "memory");
      }
      __builtin_amdgcn_sched_barrier(0);
      const char* nA = lds + ((kt + 1) & 1) * 65536;
      const char* nB = nA + 32768;
      RD_A(0, nA)
      RD_B(0, nB)
    }
  }
#undef MFMA16
#undef RD_A
#undef RD_B

  float bv[4];
  #pragma unroll
  for (int nf = 0; nf < 4; ++nf) bv[nf] = bias[col0 + wn * 64 + nf * 16 + lm];
  #pragma unroll
  for (int mf = 0; mf < 8; ++mf) {
    #pragma unroll
    for (int rr = 0; rr < 4; ++rr) {
      const int rowp = row0 + wm * 128 + mf * 16 + l4 * 4 + rr;
      #pragma unroll
      for (int nf = 0; nf < 4; ++nf) {
        float v = acc[mf][nf][rr] + bv[nf];
        v = v > 0.f ? v : 0.f;  // RELU (G1)
        Out[(size_t)rowp * Ncols + col0 + wn * 64 + nf * 16 + lm] = __float2bfloat16(v);
      }
    }
  }
}

// ---------------- launch ----------------
extern "C" void kernel_launch(void* const* d_in, const int* in_sizes, int n_in,
                              void* d_out, int out_size, void* d_ws, size_t ws_size,
                              hipStream_t stream) {
  const float* x  = (const float*)d_in[0];
  const int*   ids= (const int*)d_in[1];
  const float* W1 = (const float*)d_in[2];
  const float* b1 = (const float*)d_in[3];
  const float* W2 = (const float*)d_in[4];
  const float* b2 = (const float*)d_in[5];
  const float* W3 = (const float*)d_in[6];
  const float* b3 = (const float*)d_in[7];
  const float* W4 = (const float*)d_in[8];
  const float* b4 = (const float*)d_in[9];

  char* ws = (char*)d_ws;
  bf16* Xb  = (bf16*)(ws + OFF_XB);
  bf16* W1t = (bf16*)(ws + OFF_W1T);
  bf16* W2t = (bf16*)(ws + OFF_W2T);
  bf16* W3t = (bf16*)(ws + OFF_W3T);
  bf16* W4t = (bf16*)(ws + OFF_W4T);
  bf16* H   = (bf16*)(ws + OFF_H);
  bf16* Z   = (bf16*)(ws + OFF_Z);
  bf16* U   = (bf16*)(ws + OFF_U);   // aliases Xb/W1t/W2t/head-of-H (dead by GEMM3)
  int*  perm  = (int*)(ws + OFF_PERM);
  int*  meta  = (int*)(ws + OFF_META);
  int*  gh    = meta;
  int*  bases = meta + 512;

  // fused conversions + ids histogram
  prep_k<<<dim3(11072), dim3(256), 0, stream>>>(x, W1, W2, W3, W4, ids,
                                                Xb, W1t, W2t, W3t, W4t, gh);

  // 1) H = relu(Xb @ W1 + b1)  [16384,1024], K=512 — 256² phase-locked GEMM
  //    + embedded bucketing stripe (blockIdx.y==4): perm/bases ready before G3.
  gemm256p<<<dim3(NROWS / 256, HIDD / 256 + 1), dim3(512), 0, stream>>>(
      Xb, W1t, b1, H, HIDD, SEQD, ids, gh, perm, bases);
  // 2) Z = relu(H @ W2 + b2)   [16384,256], K=1024 — 3-slot pipeline
  gemm128<false, false, true, false, 3><<<dim3(NROWS / 128, ENCD / 128), dim3(256), 0, stream>>>(
      H, W2t, b2, Z, ENCD, HIDD, nullptr, nullptr);
  // 3) U = relu(gather(Z) @ W3[e] + b3[e])   padded rows, K=256
  gemm128<true, true, true, false, 2><<<dim3(MAXTILES, HIDD / 128), dim3(256), 0, stream>>>(
      Z, W3t, b3, U, HIDD, ENCD, perm, bases);
  // 4) y[perm] = U @ W4[e] + b4[e]   f32 scatter, K=1024
  gemm128<false, true, false, true, 2><<<dim3(MAXTILES, SEQD / 128), dim3(256), 0, stream>>>(
      U, W4t, b4, d_out, SEQD, HIDD, perm, bases);

  (void)in_sizes; (void)n_in; (void)out_size; (void)ws_size;
}

// Round 14
// 113.704 us; speedup vs baseline: 1.0073x; 1.0073x over previous
//
#include <hip/hip_runtime.h>
#include <hip/hip_bf16.h>

// Problem constants (fixed by the reference)
#define NROWS 16384
#define SEQD  512
#define HIDD  1024
#define ENCD  256
#define NEXP  8
#define NBLK  64                  // bucketing blocks (256 rows each)
#define MAXTILES 136              // 16384/128 + 8 (one partial tile per expert)
#define MPAD_MAX (MAXTILES * 128) // 17408

using bf16 = __hip_bfloat16;
typedef __bf16 bf16x8 __attribute__((ext_vector_type(8)));
typedef float  f32x4  __attribute__((ext_vector_type(4)));

// XCD-aware bijective blockIdx.x swizzle (grid.x % 8 == 0 for all our GEMMs)
__device__ __forceinline__ int xcd_swz(int bx, int gx) {
  const int cpx = gx >> 3;
  return (bx & 7) * cpx + (bx >> 3);
}

// ---------------- workspace layout (bytes) ----------------
enum : size_t {
  OFF_XB   = 0,                                  // 16384*512*2
  OFF_W1T  = OFF_XB  + (size_t)NROWS * SEQD * 2,
  OFF_W2T  = OFF_W1T + (size_t)HIDD * SEQD * 2,
  OFF_H    = OFF_W2T + (size_t)ENCD * HIDD * 2,
  OFF_W3T  = OFF_H   + (size_t)NROWS * HIDD * 2,
  OFF_W4T  = OFF_W3T + (size_t)NEXP * HIDD * ENCD * 2,
  OFF_Z    = OFF_W4T + (size_t)NEXP * SEQD * HIDD * 2,
  OFF_PERM = OFF_Z   + (size_t)NROWS * ENCD * 2,
  OFF_META = OFF_PERM + (size_t)MPAD_MAX * 4,
  OFF_U    = 0,
  WS_NEED  = OFF_META + 8192
};
// meta int layout: [0..511]=gh (per-block hist, 64x8), [512..520]=bases[9]

__device__ __forceinline__ void gload_lds16(const void* g, void* l) {
  __builtin_amdgcn_global_load_lds(
      (const __attribute__((address_space(1))) void*)g,
      (__attribute__((address_space(3))) void*)l, 16, 0, 0);
}

// ---------------- fused prep: x->bf16 + 4 weight transposes + ids histogram ----------------
// block ranges: [0,4096) cvtx | weights: +512 W1, +256 W2, +2048 W3, +4096 W4 | +64 hist
__global__ void prep_k(const float* __restrict__ x,
                       const float* __restrict__ W1, const float* __restrict__ W2,
                       const float* __restrict__ W3, const float* __restrict__ W4,
                       const int* __restrict__ ids,
                       bf16* __restrict__ Xb, bf16* __restrict__ W1t,
                       bf16* __restrict__ W2t, bf16* __restrict__ W3t,
                       bf16* __restrict__ W4t, int* __restrict__ gh) {
  __shared__ float t[32][33];
  int b = blockIdx.x;
  const int tid = threadIdx.x;
  if (b < 4096) {  // x -> bf16, 8 f32/thread (streaming, full TLP)
    size_t i = (size_t)b * 256 + tid;
    float4 a = ((const float4*)x)[i * 2];
    float4 c = ((const float4*)x)[i * 2 + 1];
    __align__(16) bf16 v[8] = {
      __float2bfloat16(a.x), __float2bfloat16(a.y), __float2bfloat16(a.z), __float2bfloat16(a.w),
      __float2bfloat16(c.x), __float2bfloat16(c.y), __float2bfloat16(c.z), __float2bfloat16(c.w)};
    *(int4*)(Xb + i * 8) = *(const int4*)v;
    return;
  }
  b -= 4096;
  if (b >= 6912) {  // ids histogram (order-invariant LDS atomics)
    __shared__ int c[NEXP];
    if (tid < NEXP) c[tid] = 0;
    __syncthreads();
    atomicAdd(&c[ids[(b - 6912) * 256 + tid]], 1);
    __syncthreads();
    if (tid < NEXP) gh[(b - 6912) * NEXP + tid] = c[tid];
    return;
  }
  const float* s; bf16* d; int R, C;
  if (b < 512)              { s = W1; d = W1t; R = SEQD; C = HIDD; }
  else if ((b -= 512) < 256){ s = W2; d = W2t; R = HIDD; C = ENCD; }
  else if ((b -= 256) < 2048){
    int z = b >> 8; b &= 255; s = W3 + (size_t)z * ENCD * HIDD; d = W3t + (size_t)z * ENCD * HIDD;
    R = ENCD; C = HIDD;
  } else {
    b -= 2048; int z = b >> 9; b &= 511;
    s = W4 + (size_t)z * HIDD * SEQD; d = W4t + (size_t)z * HIDD * SEQD;
    R = HIDD; C = SEQD;
  }
  const int nbx = C >> 5;
  const int bx = (b % nbx) * 32, by = (b / nbx) * 32;
  const int tx = tid & 31, ty = tid >> 5;
  #pragma unroll
  for (int i = 0; i < 32; i += 8) t[ty + i][tx] = s[(size_t)(by + ty + i) * C + bx + tx];
  __syncthreads();
  #pragma unroll
  for (int i = 0; i < 32; i += 8)
    d[(size_t)(bx + ty + i) * R + by + tx] = __float2bfloat16(t[tx][ty + i]);
}

// ---------------- 128x128 bf16 MFMA GEMM, N-slot counted-vmcnt (round-7/8-proven) ----------------
template <bool GATHER_A, bool EXPERT, bool RELU, bool SCATTER_F32, int NSLOTS>
__global__ __launch_bounds__(256, (NSLOTS == 2 ? 2 : 1)) void gemm128(
    const bf16* __restrict__ A, const bf16* __restrict__ Bt,
    const float* __restrict__ bias, void* __restrict__ Out,
    int Ncols, int K, const int* __restrict__ perm, const int* __restrict__ bases) {
  __shared__ char lds[NSLOTS * 32768];  // slots x (A 16KB | B 16KB); byte^=(row&7)<<4 swizzle

  const int tid  = threadIdx.x;
  const int wid  = tid >> 6;
  const int lane = tid & 63;
  const int lm = lane & 15, l4 = lane >> 4;
  const int wm = wid >> 1, wn = wid & 1;

  const int tileM = xcd_swz(blockIdx.x, gridDim.x), tileN = blockIdx.y;
  int expert = 0;
  if (EXPERT) {
    const int total = bases[8];
    if (tileM * 128 >= total) return;  // uniform early-exit, before any barrier
    const int r0 = tileM * 128;
    #pragma unroll
    for (int e = 1; e < NEXP; ++e) expert += (r0 >= bases[e]) ? 1 : 0;
    Bt   += (size_t)expert * Ncols * K;
    bias += expert * Ncols;
  }
  const int row0 = tileM * 128, col0 = tileN * 128;

  const bf16* gA[4];
  const bf16* gB[4];
  #pragma unroll
  for (int i = 0; i < 4; ++i) {
    int flat = (i * 4 + wid) * 1024 + lane * 16;
    int r    = flat >> 7;
    int cb   = (flat & 127) ^ ((r & 7) << 4);
    int arow;
    if (GATHER_A) {
      int p = perm[row0 + r];
      arow = (p < 0) ? 0 : p;
    } else {
      arow = row0 + r;
    }
    gA[i] = A  + (size_t)arow * K + (cb >> 1);
    gB[i] = Bt + (size_t)(col0 + r) * K + (cb >> 1);
  }

  f32x4 acc[4][4];
  #pragma unroll
  for (int i = 0; i < 4; ++i)
    #pragma unroll
    for (int j = 0; j < 4; ++j) { f32x4 z = {0.f, 0.f, 0.f, 0.f}; acc[i][j] = z; }

  int aoff[4], boff[4];
  const int swz = (lm & 7) << 4;
  #pragma unroll
  for (int i = 0; i < 4; ++i) {
    int ar = wm * 64 + i * 16 + lm;
    aoff[i] = ar * 128 + ((l4 * 16) ^ swz);
    int br = wn * 64 + i * 16 + lm;
    boff[i] = br * 128 + ((l4 * 16) ^ swz);
  }

  const int nk = K >> 6;
  asm volatile("s_waitcnt vmcnt(0)" ::: "memory");
  __builtin_amdgcn_sched_barrier(0);

  #pragma unroll
  for (int s = 0; s < NSLOTS; ++s) {
    if (s < nk) {
      #pragma unroll
      for (int i = 0; i < 4; ++i) {
        gload_lds16(gA[i] + (size_t)s * 64, lds + s * 32768 + (i * 4 + wid) * 1024);
        gload_lds16(gB[i] + (size_t)s * 64, lds + s * 32768 + 16384 + (i * 4 + wid) * 1024);
      }
    }
  }

  int slot = 0;
  for (int kt = 0; kt < nk; ++kt) {
    int inflight = nk - 1 - kt;
    if (inflight > NSLOTS - 1) inflight = NSLOTS - 1;
    if (inflight >= 2)      asm volatile("s_waitcnt vmcnt(16)" ::: "memory");
    else if (inflight == 1) asm volatile("s_waitcnt vmcnt(8)"  ::: "memory");
    else                    asm volatile("s_waitcnt vmcnt(0)"  ::: "memory");
    asm volatile("s_barrier" ::: "memory");
    __builtin_amdgcn_sched_barrier(0);

    const char* Ac = lds + slot * 32768;
    const char* Bc = Ac + 16384;
    #pragma unroll
    for (int kk = 0; kk < 2; ++kk) {
      bf16x8 af[4], bfr[4];
      #pragma unroll
      for (int i = 0; i < 4; ++i) af[i]  = *(const bf16x8*)(Ac + (aoff[i] ^ (kk * 64)));
      #pragma unroll
      for (int i = 0; i < 4; ++i) bfr[i] = *(const bf16x8*)(Bc + (boff[i] ^ (kk * 64)));
      #pragma unroll
      for (int mi = 0; mi < 4; ++mi)
        #pragma unroll
        for (int ni = 0; ni < 4; ++ni)
          acc[mi][ni] = __builtin_amdgcn_mfma_f32_16x16x32_bf16(af[mi], bfr[ni], acc[mi][ni], 0, 0, 0);
    }

    asm volatile("s_barrier" ::: "memory");
    __builtin_amdgcn_sched_barrier(0);
    if (kt + NSLOTS < nk) {
      char* An = lds + slot * 32768;
      #pragma unroll
      for (int i = 0; i < 4; ++i) {
        gload_lds16(gA[i] + (size_t)(kt + NSLOTS) * 64, An + (i * 4 + wid) * 1024);
        gload_lds16(gB[i] + (size_t)(kt + NSLOTS) * 64, An + 16384 + (i * 4 + wid) * 1024);
      }
    }
    slot = (slot + 1 == NSLOTS) ? 0 : slot + 1;
  }

  float bv[4];
  #pragma unroll
  for (int ni = 0; ni < 4; ++ni) bv[ni] = bias[col0 + wn * 64 + ni * 16 + lm];
  #pragma unroll
  for (int mi = 0; mi < 4; ++mi) {
    #pragma unroll
    for (int r = 0; r < 4; ++r) {
      int rowp = row0 + wm * 64 + mi * 16 + l4 * 4 + r;
      int orow = rowp;
      bool valid = true;
      if (SCATTER_F32) {
        int p = perm[rowp];
        valid = (p >= 0);
        orow  = valid ? p : 0;
      }
      #pragma unroll
      for (int ni = 0; ni < 4; ++ni) {
        float v = acc[mi][ni][r] + bv[ni];
        if (RELU) v = v > 0.f ? v : 0.f;
        int n = col0 + wn * 64 + ni * 16 + lm;
        if (SCATTER_F32) {
          if (valid) ((float*)Out)[(size_t)orow * Ncols + n] = v;
        } else {
          ((bf16*)Out)[(size_t)rowp * Ncols + n] = __float2bfloat16(v);
        }
      }
    }
  }
}

// ---------------- 256x256 8-wave phase-locked GEMM (G1) + embedded bucketing stripe ----------------
__global__ __launch_bounds__(512, 2) void gemm256p(
    const bf16* __restrict__ A, const bf16* __restrict__ Bt,
    const float* __restrict__ bias, bf16* __restrict__ Out, int Ncols, int K,
    const int* __restrict__ ids, const int* __restrict__ gh,
    int* __restrict__ perm, int* __restrict__ bases_g) {
  __shared__ char lds[131072];

  const int tid  = threadIdx.x;

  if (blockIdx.y == 4) {  // ---- bucketing stripe (round-11-proven) ----
    __shared__ int counts_s[NEXP];
    __shared__ int base_s[NEXP + 1];
    __shared__ int myb[NEXP];
    __shared__ int wavehist[4][NEXP];
    const int bx = blockIdx.x;  // 0..63
    if (tid < NEXP) {
      int s = 0, run = 0;
      for (int b = 0; b < NBLK; ++b) {
        int g = gh[b * NEXP + tid];
        if (b < bx) run += g;
        s += g;
      }
      counts_s[tid] = s;
      myb[tid] = run;
    }
    __syncthreads();
    if (tid == 0) {
      int t = 0;
      for (int e = 0; e < NEXP; ++e) { base_s[e] = t; t += (counts_s[e] + 127) & ~127; }
      base_s[NEXP] = t;
    }
    __syncthreads();
    if (tid < NEXP) myb[tid] += base_s[tid];
    if (bx == 0) {
      if (tid <= NEXP) bases_g[tid] = base_s[tid];
      #pragma unroll
      for (int e = 0; e < NEXP; ++e) {
        int i = base_s[e] + counts_s[e] + tid;
        if (i < base_s[e + 1]) perm[i] = -1;
      }
    }
    __syncthreads();
    const int w = tid >> 6, lane = tid & 63;
    const unsigned long long lt = (1ull << lane) - 1ull;
    int e = 0, myrank = 0;
    if (w < 4) {
      e = ids[bx * 256 + tid];
      #pragma unroll
      for (int ee = 0; ee < NEXP; ++ee) {
        unsigned long long bb = __ballot(e == ee);
        if (ee == e) myrank = __popcll(bb & lt);
        if (lane == 0) wavehist[w][ee] = __popcll(bb);
      }
    }
    __syncthreads();
    if (w < 4) {
      int pre = 0;
      for (int w2 = 0; w2 < w; ++w2) pre += wavehist[w2][e];
      perm[myb[e] + pre + myrank] = bx * 256 + tid;
    }
    return;
  }

  // ---- GEMM path (round-10-proven) ----
  const int wid  = tid >> 6;
  const int lane = tid & 63;
  const int lm = lane & 15, l4 = lane >> 4;
  const int wm = wid >> 2, wn = wid & 3;
  const int tileM = xcd_swz(blockIdx.x, gridDim.x);
  const int row0 = tileM * 256, col0 = blockIdx.y * 256;

  const bf16* gA[4];
  const bf16* gB[4];
  #pragma unroll
  for (int i = 0; i < 4; ++i) {
    const int flat = i * 8192 + tid * 16;
    const int r    = flat >> 7;
    const int cb   = (flat & 127) ^ ((r & 7) << 4);
    gA[i] = A  + (size_t)(row0 + r) * K + (cb >> 1);
    gB[i] = Bt + (size_t)(col0 + r) * K + (cb >> 1);
  }

  f32x4 acc[8][4];
  #pragma unroll
  for (int i = 0; i < 8; ++i)
    #pragma unroll
    for (int j = 0; j < 4; ++j) { f32x4 z = {0.f, 0.f, 0.f, 0.f}; acc[i][j] = z; }

  int aoff[2][4], boff[2][2];
  #pragma unroll
  for (int h = 0; h < 2; ++h)
    #pragma unroll
    for (int q = 0; q < 4; ++q) {
      int row = wm * 128 + h * 64 + q * 16 + lm;
      aoff[h][q] = row * 128 + ((l4 * 16) ^ ((row & 7) << 4));
    }
  #pragma unroll
  for (int nh = 0; nh < 2; ++nh)
    #pragma unroll
    for (int p = 0; p < 2; ++p) {
      int row = wn * 64 + nh * 32 + p * 16 + lm;
      boff[nh][p] = row * 128 + ((l4 * 16) ^ ((row & 7) << 4));
    }

  const int nk = K >> 6;
  asm volatile("s_waitcnt vmcnt(0)" ::: "memory");
  __builtin_amdgcn_sched_barrier(0);

  #pragma unroll
  for (int i = 0; i < 4; ++i) {
    gload_lds16(gA[i], lds + i * 8192 + tid * 16);
    gload_lds16(gB[i], lds + 32768 + i * 8192 + tid * 16);
  }
  #pragma unroll
  for (int i = 0; i < 4; ++i) {
    gload_lds16(gA[i] + 64, lds + 65536 + i * 8192 + tid * 16);
    gload_lds16(gB[i] + 64, lds + 65536 + 32768 + i * 8192 + tid * 16);
  }
  asm volatile("s_waitcnt vmcnt(8)" ::: "memory");
  asm volatile("s_barrier" ::: "memory");
  __builtin_amdgcn_sched_barrier(0);

  bf16x8 a[4][2], b[2][2];
  #pragma unroll
  for (int q = 0; q < 4; ++q)
    #pragma unroll
    for (int kk = 0; kk < 2; ++kk) a[q][kk] = *(const bf16x8*)(lds + (aoff[0][q] ^ (kk * 64)));
  #pragma unroll
  for (int p = 0; p < 2; ++p)
    #pragma unroll
    for (int kk = 0; kk < 2; ++kk) b[p][kk] = *(const bf16x8*)(lds + 32768 + (boff[0][p] ^ (kk * 64)));

#define MFMA16(MOFF, NOFF)                                                      \
  __builtin_amdgcn_s_setprio(1);                                                \
  _Pragma("unroll")                                                             \
  for (int kk = 0; kk < 2; ++kk)                                                \
    _Pragma("unroll")                                                           \
    for (int mf = 0; mf < 4; ++mf)                                              \
      _Pragma("unroll")                                                         \
      for (int nf = 0; nf < 2; ++nf)                                            \
        acc[MOFF + mf][NOFF + nf] = __builtin_amdgcn_mfma_f32_16x16x32_bf16(    \
            a[mf][kk], b[nf][kk], acc[MOFF + mf][NOFF + nf], 0, 0, 0);          \
  __builtin_amdgcn_s_setprio(0);

#define RD_A(H, BUFA)                                                           \
  _Pragma("unroll")                                                             \
  for (int q = 0; q < 4; ++q)                                                   \
    _Pragma("unroll")                                                           \
    for (int kk = 0; kk < 2; ++kk)                                              \
      a[q][kk] = *(const bf16x8*)((BUFA) + (aoff[H][q] ^ (kk * 64)));
#define RD_B(NH, BUFB)                                                          \
  _Pragma("unroll")                                                             \
  for (int p = 0; p < 2; ++p)                                                   \
    _Pragma("unroll")                                                           \
    for (int kk = 0; kk < 2; ++kk)                                              \
      b[p][kk] = *(const bf16x8*)((BUFB) + (boff[NH][p] ^ (kk * 64)));

  for (int kt = 0; kt < nk; ++kt) {
    const char* bufA = lds + (kt & 1) * 65536;
    const char* bufB = bufA + 32768;
    asm volatile("s_barrier" ::: "memory");
    MFMA16(0, 0)
    RD_B(1, bufB)
    asm volatile("s_barrier" ::: "memory");
    MFMA16(0, 2)
    RD_A(1, bufA)
    asm volatile("s_barrier" ::: "memory");
    MFMA16(4, 2)
    RD_B(0, bufB)
    asm volatile("s_barrier" ::: "memory");
    MFMA16(4, 0)
    if (kt + 1 < nk) {
      asm volatile("s_waitcnt lgkmcnt(0)" ::: "memory");
      asm volatile("s_barrier" ::: "memory");
      __builtin_amdgcn_sched_barrier(0);
      if (kt + 2 < nk) {
        char* sA = lds + (kt & 1) * 65536;
        #pragma unroll
        for (int i = 0; i < 4; ++i) {
          gload_lds16(gA[i] + (size_t)(kt + 2) * 64, sA + i * 8192 + tid * 16);
          gload_lds16(gB[i] + (size_t)(kt + 2) * 64, sA + 32768 + i * 8192 + tid * 16);
        }
        asm volatile("s_waitcnt vmcnt(8)" ::: "memory");
      } else {
        asm volatile("s_waitcnt vmcnt(0)" ::: "memory");
      }
      __builtin_amdgcn_sched_barrier(0);
      const char* nA = lds + ((kt + 1) & 1) * 65536;
      const char* nB = nA + 32768;
      RD_A(0, nA)
      RD_B(0, nB)
    }
  }
#undef MFMA16
#undef RD_A
#undef RD_B

  float bv[4];
  #pragma unroll
  for (int nf = 0; nf < 4; ++nf) bv[nf] = bias[col0 + wn * 64 + nf * 16 + lm];
  #pragma unroll
  for (int mf = 0; mf < 8; ++mf) {
    #pragma unroll
    for (int rr = 0; rr < 4; ++rr) {
      const int rowp = row0 + wm * 128 + mf * 16 + l4 * 4 + rr;
      #pragma unroll
      for (int nf = 0; nf < 4; ++nf) {
        float v = acc[mf][nf][rr] + bv[nf];
        v = v > 0.f ? v : 0.f;  // RELU (G1)
        Out[(size_t)rowp * Ncols + col0 + wn * 64 + nf * 16 + lm] = __float2bfloat16(v);
      }
    }
  }
}

// ---------------- launch ----------------
extern "C" void kernel_launch(void* const* d_in, const int* in_sizes, int n_in,
                              void* d_out, int out_size, void* d_ws, size_t ws_size,
                              hipStream_t stream) {
  const float* x  = (const float*)d_in[0];
  const int*   ids= (const int*)d_in[1];
  const float* W1 = (const float*)d_in[2];
  const float* b1 = (const float*)d_in[3];
  const float* W2 = (const float*)d_in[4];
  const float* b2 = (const float*)d_in[5];
  const float* W3 = (const float*)d_in[6];
  const float* b3 = (const float*)d_in[7];
  const float* W4 = (const float*)d_in[8];
  const float* b4 = (const float*)d_in[9];

  char* ws = (char*)d_ws;
  bf16* Xb  = (bf16*)(ws + OFF_XB);
  bf16* W1t = (bf16*)(ws + OFF_W1T);
  bf16* W2t = (bf16*)(ws + OFF_W2T);
  bf16* W3t = (bf16*)(ws + OFF_W3T);
  bf16* W4t = (bf16*)(ws + OFF_W4T);
  bf16* H   = (bf16*)(ws + OFF_H);
  bf16* Z   = (bf16*)(ws + OFF_Z);
  bf16* U   = (bf16*)(ws + OFF_U);   // aliases Xb/W1t/W2t/head-of-H (dead by GEMM3)
  int*  perm  = (int*)(ws + OFF_PERM);
  int*  meta  = (int*)(ws + OFF_META);
  int*  gh    = meta;
  int*  bases = meta + 512;

  // fused conversions + ids histogram
  prep_k<<<dim3(11072), dim3(256), 0, stream>>>(x, W1, W2, W3, W4, ids,
                                                Xb, W1t, W2t, W3t, W4t, gh);

  // 1) H = relu(Xb @ W1 + b1)  [16384,1024], K=512 — 256² phase-locked GEMM
  //    + embedded bucketing stripe (blockIdx.y==4): perm/bases ready before G3.
  gemm256p<<<dim3(NROWS / 256, HIDD / 256 + 1), dim3(512), 0, stream>>>(
      Xb, W1t, b1, H, HIDD, SEQD, ids, gh, perm, bases);
  // 2) Z = relu(H @ W2 + b2)   [16384,256], K=1024 — 3-slot pipeline
  gemm128<false, false, true, false, 3><<<dim3(NROWS / 128, ENCD / 128), dim3(256), 0, stream>>>(
      H, W2t, b2, Z, ENCD, HIDD, nullptr, nullptr);
  // 3) U = relu(gather(Z) @ W3[e] + b3[e])   padded rows, K=256
  gemm128<true, true, true, false, 2><<<dim3(MAXTILES, HIDD / 128), dim3(256), 0, stream>>>(
      Z, W3t, b3, U, HIDD, ENCD, perm, bases);
  // 4) y[perm] = U @ W4[e] + b4[e]   f32 scatter, K=1024
  gemm128<false, true, false, true, 2><<<dim3(MAXTILES, SEQD / 128), dim3(256), 0, stream>>>(
      U, W4t, b4, d_out, SEQD, HIDD, perm, bases);

  (void)in_sizes; (void)n_in; (void)out_size; (void)ws_size;
}